// Round 1
// baseline (350.942 us; speedup 1.0000x reference)
//
#include <hip/hip_runtime.h>
#include <hip/hip_fp16.h>
#include <stdint.h>

typedef _Float16 f16;
typedef __attribute__((ext_vector_type(8))) _Float16 f16x8;
typedef __attribute__((ext_vector_type(4))) _Float16 f16x4;
typedef __attribute__((ext_vector_type(4))) float f32x4;

#define HD 1024
#define NH 16
#define DH 64
#define BB 2
#define MM 2048
#define BH (BB*NH)          // 32
#define MT (BB*MM)          // 4096 total rows

// ---------------- fp32 -> fp16 conversion ----------------
__global__ void cvt_f32_f16(const float* __restrict__ in, f16* __restrict__ out, int n4) {
    int i = blockIdx.x * blockDim.x + threadIdx.x;
    if (i >= n4) return;
    float4 v = ((const float4*)in)[i];
    f16x4 h;
    h[0] = (f16)v.x; h[1] = (f16)v.y; h[2] = (f16)v.z; h[3] = (f16)v.w;
    ((f16x4*)out)[i] = h;
}

// ---------------- projection GEMM: C[m,n] = sum_k A[m,k] * W[n,k] + bias[n] ----------------
// A: [4096][1024] f16, W: [1024][1024] f16 (row n along k), bias f32.
// VT=false: out[((b*16+h)*2048+mm)*64+dh] (Q/K layout)
// VT=true : out[((b*16+h)*64+dh)*2048+mm] (V transposed)
template<bool VT>
__global__ __launch_bounds__(256) void proj_gemm(const f16* __restrict__ A,
                                                 const f16* __restrict__ W,
                                                 const float* __restrict__ bias,
                                                 f16* __restrict__ out) {
    __shared__ f16 As[128][40];   // +8 pad: kills bank conflicts on ds_read_b128
    __shared__ f16 Bs[128][40];
    const int bn = blockIdx.x, bm = blockIdx.y;
    const int t = threadIdx.x;
    const int wid = t >> 6, lane = t & 63;
    const int wr = wid >> 1, wc = wid & 1;      // 2x2 wave grid, 64x64 each
    const int lg = lane >> 4, lr = lane & 15;
    f32x4 acc[4][4] = {};

    const int sr = t >> 2;           // 0..63
    const int sc = (t & 3) * 8;      // 0,8,16,24
    const f16* Ag = A + (size_t)(bm * 128 + sr) * HD + sc;
    const f16* Wg = W + (size_t)(bn * 128 + sr) * HD + sc;

    for (int k0 = 0; k0 < HD; k0 += 32) {
        f16x8 a0 = *(const f16x8*)(Ag + k0);
        f16x8 a1 = *(const f16x8*)(Ag + (size_t)64 * HD + k0);
        f16x8 b0 = *(const f16x8*)(Wg + k0);
        f16x8 b1 = *(const f16x8*)(Wg + (size_t)64 * HD + k0);
        __syncthreads();                // previous iter's frag reads done
        *(f16x8*)(&As[sr][sc]) = a0;
        *(f16x8*)(&As[sr + 64][sc]) = a1;
        *(f16x8*)(&Bs[sr][sc]) = b0;
        *(f16x8*)(&Bs[sr + 64][sc]) = b1;
        __syncthreads();
        f16x8 af[4], bf[4];
        #pragma unroll
        for (int i = 0; i < 4; i++) af[i] = *(const f16x8*)(&As[wr * 64 + i * 16 + lr][lg * 8]);
        #pragma unroll
        for (int i = 0; i < 4; i++) bf[i] = *(const f16x8*)(&Bs[wc * 64 + i * 16 + lr][lg * 8]);
        #pragma unroll
        for (int i = 0; i < 4; i++)
            #pragma unroll
            for (int j = 0; j < 4; j++)
                acc[i][j] = __builtin_amdgcn_mfma_f32_16x16x32_f16(af[i], bf[j], acc[i][j], 0, 0, 0);
    }

    #pragma unroll
    for (int i = 0; i < 4; i++) {
        #pragma unroll
        for (int j = 0; j < 4; j++) {
            int n = bn * 128 + wc * 64 + j * 16 + lr;
            float bv = bias[n];
            int h = n >> 6, dh = n & 63;
            #pragma unroll
            for (int r = 0; r < 4; r++) {
                int mg = bm * 128 + wr * 64 + i * 16 + lg * 4 + r;
                int b = mg >> 11, mmr = mg & 2047;
                float v = acc[i][j][r] + bv;
                if (VT) out[((size_t)((b * NH + h) * DH + dh)) * MM + mmr] = (f16)v;
                else    out[((size_t)((b * NH + h) * MM + mmr)) * DH + dh] = (f16)v;
            }
        }
    }
}

// ---------------- flash attention ----------------
// Q,K: [32][2048][64] f16; Vt: [32][64][2048] f16; ctx out: [4096][1024] f16
__global__ __launch_bounds__(256) void attn_kernel(const f16* __restrict__ Q,
                                                   const f16* __restrict__ Kt,
                                                   const f16* __restrict__ Vt,
                                                   f16* __restrict__ ctx) {
    __shared__ f16 Pl[4][16][72];    // per-wave P transpose staging, padded
    const int bh = blockIdx.y;
    const int qb = blockIdx.x * 64;
    const int t = threadIdx.x, w = t >> 6, lane = t & 63;
    const int lg = lane >> 4, lr = lane & 15;
    const int q0 = qb + w * 16;

    const f16* Qb = Q + (size_t)bh * MM * DH;
    const f16* Kb = Kt + (size_t)bh * MM * DH;
    const f16* Vb = Vt + (size_t)bh * DH * MM;

    f16x8 qf[2];
    #pragma unroll
    for (int kc = 0; kc < 2; kc++)
        qf[kc] = *(const f16x8*)(Qb + (size_t)(q0 + lr) * DH + kc * 32 + lg * 8);

    f32x4 po[4] = {};
    float mrow[4], lrow[4];
    #pragma unroll
    for (int r = 0; r < 4; r++) { mrow[r] = -1e30f; lrow[r] = 0.f; }

    for (int j0 = 0; j0 < MM; j0 += 64) {
        // S = Q K^T  (16x64 per wave)
        f32x4 s[4];
        #pragma unroll
        for (int f = 0; f < 4; f++) {
            f16x8 kf0 = *(const f16x8*)(Kb + (size_t)(j0 + f * 16 + lr) * DH + lg * 8);
            f16x8 kf1 = *(const f16x8*)(Kb + (size_t)(j0 + f * 16 + lr) * DH + 32 + lg * 8);
            f32x4 z = {};
            z = __builtin_amdgcn_mfma_f32_16x16x32_f16(qf[0], kf0, z, 0, 0, 0);
            z = __builtin_amdgcn_mfma_f32_16x16x32_f16(qf[1], kf1, z, 0, 0, 0);
            s[f] = z;
        }
        // scale + multiplicative diag-zero mask (s[i][i] = 0, BEFORE max)
        #pragma unroll
        for (int f = 0; f < 4; f++)
            #pragma unroll
            for (int r = 0; r < 4; r++) {
                float v = s[f][r] * 0.125f;
                int qg = q0 + lg * 4 + r;
                int jg = j0 + f * 16 + lr;
                s[f][r] = (qg == jg) ? 0.f : v;
            }
        // row max (16 lanes of group lg share rows lg*4+r)
        float nm[4], al[4], rs[4];
        #pragma unroll
        for (int r = 0; r < 4; r++) {
            float mx = fmaxf(fmaxf(s[0][r], s[1][r]), fmaxf(s[2][r], s[3][r]));
            mx = fmaxf(mx, __shfl_xor(mx, 1));
            mx = fmaxf(mx, __shfl_xor(mx, 2));
            mx = fmaxf(mx, __shfl_xor(mx, 4));
            mx = fmaxf(mx, __shfl_xor(mx, 8));
            nm[r] = fmaxf(mrow[r], mx);
            al[r] = __expf(mrow[r] - nm[r]);
            mrow[r] = nm[r];
        }
        #pragma unroll
        for (int r = 0; r < 4; r++) rs[r] = 0.f;
        #pragma unroll
        for (int f = 0; f < 4; f++)
            #pragma unroll
            for (int r = 0; r < 4; r++) {
                float p = __expf(s[f][r] - nm[r]);
                rs[r] += p;
                Pl[w][lg * 4 + r][f * 16 + lr] = (f16)p;
            }
        #pragma unroll
        for (int r = 0; r < 4; r++) {
            float x = rs[r];
            x += __shfl_xor(x, 1); x += __shfl_xor(x, 2);
            x += __shfl_xor(x, 4); x += __shfl_xor(x, 8);
            lrow[r] = lrow[r] * al[r] + x;
        }
        #pragma unroll
        for (int d = 0; d < 4; d++)
            #pragma unroll
            for (int r = 0; r < 4; r++) po[d][r] *= al[r];
        asm volatile("s_waitcnt lgkmcnt(0)" ::: "memory");   // wave-local LDS visibility
        // PV: context += P * V
        f16x8 pa[2];
        #pragma unroll
        for (int kc = 0; kc < 2; kc++)
            pa[kc] = *(const f16x8*)(&Pl[w][lr][kc * 32 + lg * 8]);
        #pragma unroll
        for (int d = 0; d < 4; d++) {
            f16x8 v0 = *(const f16x8*)(Vb + (size_t)(d * 16 + lr) * MM + j0 + lg * 8);
            f16x8 v1 = *(const f16x8*)(Vb + (size_t)(d * 16 + lr) * MM + j0 + 32 + lg * 8);
            po[d] = __builtin_amdgcn_mfma_f32_16x16x32_f16(pa[0], v0, po[d], 0, 0, 0);
            po[d] = __builtin_amdgcn_mfma_f32_16x16x32_f16(pa[1], v1, po[d], 0, 0, 0);
        }
    }
    const int b = bh >> 4, h = bh & 15;
    #pragma unroll
    for (int d = 0; d < 4; d++)
        #pragma unroll
        for (int r = 0; r < 4; r++) {
            int mmr = q0 + lg * 4 + r;
            float v = po[d][r] / lrow[r];
            ctx[((size_t)(b * MM + mmr)) * HD + h * DH + d * 16 + lr] = (f16)v;
        }
}

// ---------------- output GEMM: out[m,n] = sum_k ctx[m,k] * Wo[n,k] + bo[n] (fp32 out) ----------------
__global__ __launch_bounds__(256) void out_gemm(const f16* __restrict__ A,
                                                const f16* __restrict__ W,
                                                const float* __restrict__ bias,
                                                float* __restrict__ out) {
    __shared__ f16 As[128][40];
    __shared__ f16 Bs[128][40];
    const int bn = blockIdx.x, bm = blockIdx.y;
    const int t = threadIdx.x;
    const int wid = t >> 6, lane = t & 63;
    const int wr = wid >> 1, wc = wid & 1;
    const int lg = lane >> 4, lr = lane & 15;
    f32x4 acc[4][4] = {};

    const int sr = t >> 2;
    const int sc = (t & 3) * 8;
    const f16* Ag = A + (size_t)(bm * 128 + sr) * HD + sc;
    const f16* Wg = W + (size_t)(bn * 128 + sr) * HD + sc;

    for (int k0 = 0; k0 < HD; k0 += 32) {
        f16x8 a0 = *(const f16x8*)(Ag + k0);
        f16x8 a1 = *(const f16x8*)(Ag + (size_t)64 * HD + k0);
        f16x8 b0 = *(const f16x8*)(Wg + k0);
        f16x8 b1 = *(const f16x8*)(Wg + (size_t)64 * HD + k0);
        __syncthreads();
        *(f16x8*)(&As[sr][sc]) = a0;
        *(f16x8*)(&As[sr + 64][sc]) = a1;
        *(f16x8*)(&Bs[sr][sc]) = b0;
        *(f16x8*)(&Bs[sr + 64][sc]) = b1;
        __syncthreads();
        f16x8 af[4], bf[4];
        #pragma unroll
        for (int i = 0; i < 4; i++) af[i] = *(const f16x8*)(&As[wr * 64 + i * 16 + lr][lg * 8]);
        #pragma unroll
        for (int i = 0; i < 4; i++) bf[i] = *(const f16x8*)(&Bs[wc * 64 + i * 16 + lr][lg * 8]);
        #pragma unroll
        for (int i = 0; i < 4; i++)
            #pragma unroll
            for (int j = 0; j < 4; j++)
                acc[i][j] = __builtin_amdgcn_mfma_f32_16x16x32_f16(af[i], bf[j], acc[i][j], 0, 0, 0);
    }

    #pragma unroll
    for (int i = 0; i < 4; i++)
        #pragma unroll
        for (int j = 0; j < 4; j++) {
            int n = bn * 128 + wc * 64 + j * 16 + lr;
            float bv = bias[n];
            #pragma unroll
            for (int r = 0; r < 4; r++) {
                int mg = bm * 128 + wr * 64 + i * 16 + lg * 4 + r;
                out[(size_t)mg * HD + n] = acc[i][j][r] + bv;
            }
        }
}

extern "C" void kernel_launch(void* const* d_in, const int* in_sizes, int n_in,
                              void* d_out, int out_size, void* d_ws, size_t ws_size,
                              hipStream_t stream) {
    const float* x  = (const float*)d_in[0];
    const float* Wq = (const float*)d_in[1];
    const float* bq = (const float*)d_in[2];
    const float* Wk = (const float*)d_in[3];
    const float* bk = (const float*)d_in[4];
    const float* Wv = (const float*)d_in[5];
    const float* bv = (const float*)d_in[6];
    const float* Wo = (const float*)d_in[7];
    const float* bo = (const float*)d_in[8];
    float* out = (float*)d_out;

    f16* xh  = (f16*)d_ws;                       // 4096*1024
    f16* wqh = xh  + (size_t)MT * HD;            // 1024*1024
    f16* wkh = wqh + (size_t)HD * HD;
    f16* wvh = wkh + (size_t)HD * HD;
    f16* woh = wvh + (size_t)HD * HD;
    f16* Qh  = woh + (size_t)HD * HD;            // 32*2048*64
    f16* Kh  = Qh  + (size_t)BH * MM * DH;
    f16* Vth = Kh  + (size_t)BH * MM * DH;
    f16* ctxh= Vth + (size_t)BH * MM * DH;       // 4096*1024

    const int xn4 = MT * HD / 4, wn4 = HD * HD / 4;
    cvt_f32_f16<<<(xn4 + 255) / 256, 256, 0, stream>>>(x, xh, xn4);
    cvt_f32_f16<<<(wn4 + 255) / 256, 256, 0, stream>>>(Wq, wqh, wn4);
    cvt_f32_f16<<<(wn4 + 255) / 256, 256, 0, stream>>>(Wk, wkh, wn4);
    cvt_f32_f16<<<(wn4 + 255) / 256, 256, 0, stream>>>(Wv, wvh, wn4);
    cvt_f32_f16<<<(wn4 + 255) / 256, 256, 0, stream>>>(Wo, woh, wn4);

    dim3 gg(HD / 128, MT / 128);   // (8, 32)
    proj_gemm<false><<<gg, 256, 0, stream>>>(xh, wqh, bq, Qh);
    proj_gemm<false><<<gg, 256, 0, stream>>>(xh, wkh, bk, Kh);
    proj_gemm<true ><<<gg, 256, 0, stream>>>(xh, wvh, bv, Vth);

    attn_kernel<<<dim3(MM / 64, BH), 256, 0, stream>>>(Qh, Kh, Vth, ctxh);

    out_gemm<<<gg, 256, 0, stream>>>(ctxh, woh, bo, out);
}

// Round 2
// 181.317 us; speedup vs baseline: 1.9355x; 1.9355x over previous
//
#include <hip/hip_runtime.h>
#include <stdint.h>

typedef _Float16 f16;
typedef __attribute__((ext_vector_type(8))) _Float16 f16x8;
typedef __attribute__((ext_vector_type(4))) _Float16 f16x4;
typedef __attribute__((ext_vector_type(4))) float f32x4;

#define HD 1024
#define NH 16
#define DH 64
#define BB 2
#define MM 2048
#define BH (BB*NH)          // 32
#define MT (BB*MM)          // 4096 total rows

// ---------------- fp32 -> fp16 conversion ----------------
__global__ void cvt_f32_f16(const float* __restrict__ in, f16* __restrict__ out, int n4) {
    int i = blockIdx.x * blockDim.x + threadIdx.x;
    if (i >= n4) return;
    float4 v = ((const float4*)in)[i];
    f16x4 h;
    h[0] = (f16)v.x; h[1] = (f16)v.y; h[2] = (f16)v.z; h[3] = (f16)v.w;
    ((f16x4*)out)[i] = h;
}

// ---------------- projection GEMM: C[m,n] = sum_k A[m,k] * W[n,k] + bias[n] ----------------
// VT=false: out[((b*16+h)*2048+mm)*64+dh] (Q/K layout);  VT=true: out[((b*16+h)*64+dh)*2048+mm] (V^T)
// SC: multiply result by 1/8 (fold attention scale into Q)
template<bool VT, bool SC>
__global__ __launch_bounds__(256) void proj_gemm(const f16* __restrict__ A,
                                                 const f16* __restrict__ W,
                                                 const float* __restrict__ bias,
                                                 f16* __restrict__ out) {
    __shared__ f16 As[128][40];
    __shared__ f16 Bs[128][40];
    const int bn = blockIdx.x, bm = blockIdx.y;
    const int t = threadIdx.x;
    const int wid = t >> 6, lane = t & 63;
    const int wr = wid >> 1, wc = wid & 1;
    const int lg = lane >> 4, lr = lane & 15;
    f32x4 acc[4][4] = {};

    const int sr = t >> 2;
    const int sc = (t & 3) * 8;
    const f16* Ag = A + (size_t)(bm * 128 + sr) * HD + sc;
    const f16* Wg = W + (size_t)(bn * 128 + sr) * HD + sc;

    for (int k0 = 0; k0 < HD; k0 += 32) {
        f16x8 a0 = *(const f16x8*)(Ag + k0);
        f16x8 a1 = *(const f16x8*)(Ag + (size_t)64 * HD + k0);
        f16x8 b0 = *(const f16x8*)(Wg + k0);
        f16x8 b1 = *(const f16x8*)(Wg + (size_t)64 * HD + k0);
        __syncthreads();
        *(f16x8*)(&As[sr][sc]) = a0;
        *(f16x8*)(&As[sr + 64][sc]) = a1;
        *(f16x8*)(&Bs[sr][sc]) = b0;
        *(f16x8*)(&Bs[sr + 64][sc]) = b1;
        __syncthreads();
        f16x8 af[4], bf[4];
        #pragma unroll
        for (int i = 0; i < 4; i++) af[i] = *(const f16x8*)(&As[wr * 64 + i * 16 + lr][lg * 8]);
        #pragma unroll
        for (int i = 0; i < 4; i++) bf[i] = *(const f16x8*)(&Bs[wc * 64 + i * 16 + lr][lg * 8]);
        #pragma unroll
        for (int i = 0; i < 4; i++)
            #pragma unroll
            for (int j = 0; j < 4; j++)
                acc[i][j] = __builtin_amdgcn_mfma_f32_16x16x32_f16(af[i], bf[j], acc[i][j], 0, 0, 0);
    }

    #pragma unroll
    for (int i = 0; i < 4; i++) {
        #pragma unroll
        for (int j = 0; j < 4; j++) {
            int n = bn * 128 + wc * 64 + j * 16 + lr;
            float bv = bias[n];
            int h = n >> 6, dh = n & 63;
            #pragma unroll
            for (int r = 0; r < 4; r++) {
                int mg = bm * 128 + wr * 64 + i * 16 + lg * 4 + r;
                int b = mg >> 11, mmr = mg & 2047;
                float v = acc[i][j][r] + bv;
                if (SC) v *= 0.125f;
                if (VT) out[((size_t)((b * NH + h) * DH + dh)) * MM + mmr] = (f16)v;
                else    out[((size_t)((b * NH + h) * MM + mmr)) * DH + dh] = (f16)v;
            }
        }
    }
}

// ---------------- flash attention (swapped-operand, LDS dbuf staging) ----------------
// Q,K: [32][2048][64] f16 (Q pre-scaled by 1/8); Vt: [32][64][2048] f16; ctx out: [4096][1024] f16
__device__ __forceinline__ void gl_lds16(const f16* g, f16* l) {
    __builtin_amdgcn_global_load_lds((const __attribute__((address_space(1))) uint32_t*)g,
                                     (__attribute__((address_space(3))) uint32_t*)l, 16, 0, 0);
}

__global__ __launch_bounds__(256, 2) void attn_kernel(const f16* __restrict__ Q,
                                                      const f16* __restrict__ K,
                                                      const f16* __restrict__ Vt,
                                                      f16* __restrict__ ctx) {
    __shared__ f16 Kl[2][64][64];   // [buf][kv][dh], cols XOR-swizzled by (row&7)<<3
    __shared__ f16 Vl[2][64][64];   // [buf][dh][kv], same swizzle
    __shared__ f16 Pl[4][32][64];   // per-wave [q][kv], same swizzle
    const int bh = blockIdx.y;
    const int qb = blockIdx.x * 128;
    const int t = threadIdx.x, w = t >> 6, lane = t & 63;
    const int lr = lane & 15, lg = lane >> 4;
    const int wq0 = qb + w * 32;

    const f16* Qb = Q + (size_t)bh * MM * DH;
    const f16* Kb = K + (size_t)bh * MM * DH;
    const f16* Vb = Vt + (size_t)bh * DH * MM;

    // staging: lane covers row = w*16+i*8+(lane>>3), 16B chunk (lane&7); source col pre-swizzled
    const int srow = lane >> 3;                       // 0..7
    const int sxc = ((lane & 7) ^ srow) * 8;          // f16 units

    // Q fragments (B-operand): lane holds Q[q=wq0+qf*16+lr][dh=c*32+lg*8+j]
    f16x8 qfr[2][2];
    #pragma unroll
    for (int qf = 0; qf < 2; qf++)
        #pragma unroll
        for (int c = 0; c < 2; c++)
            qfr[qf][c] = *(const f16x8*)(Qb + (size_t)(wq0 + qf * 16 + lr) * DH + c * 32 + lg * 8);

    f32x4 po[2][4] = {};                 // ctx^T frags: D[d][q], row=d=lg*4+r, col=q=lr
    float m_[2] = {-1e30f, -1e30f}, l_[2] = {0.f, 0.f};

    // prologue: stage tile 0 into buf 0
    #pragma unroll
    for (int i = 0; i < 2; i++) {
        int row = w * 16 + i * 8 + srow;
        gl_lds16(Kb + (size_t)row * DH + sxc, &Kl[0][w * 16 + i * 8][0]);
        gl_lds16(Vb + (size_t)row * MM + sxc, &Vl[0][w * 16 + i * 8][0]);
    }
    __syncthreads();

    const int sw = (lr & 7) * 8;   // read-side swizzle (f16 units)

    for (int it = 0; it < 32; ++it) {
        const int j0 = it * 64;
        const int cur = it & 1;
        // prefetch next tile (overlaps this iter's compute; drained by end-of-iter barrier)
        if (it < 31) {
            #pragma unroll
            for (int i = 0; i < 2; i++) {
                int row = w * 16 + i * 8 + srow;
                gl_lds16(Kb + (size_t)(j0 + 64 + row) * DH + sxc, &Kl[cur ^ 1][w * 16 + i * 8][0]);
                gl_lds16(Vb + (size_t)row * MM + j0 + 64 + sxc, &Vl[cur ^ 1][w * 16 + i * 8][0]);
            }
        }
        // S^T = K_tile x Q : sa[f][qf], lane holds q=lr(+16qf), kv=f*16+lg*4+r
        f32x4 sa[4][2] = {};
        #pragma unroll
        for (int f = 0; f < 4; f++) {
            const f16* kr = &Kl[cur][f * 16 + lr][0];
            f16x8 k0 = *(const f16x8*)(kr + ((lg * 8) ^ sw));
            f16x8 k1 = *(const f16x8*)(kr + ((32 + lg * 8) ^ sw));
            #pragma unroll
            for (int qf = 0; qf < 2; qf++) {
                sa[f][qf] = __builtin_amdgcn_mfma_f32_16x16x32_f16(k0, qfr[qf][0], sa[f][qf], 0, 0, 0);
                sa[f][qf] = __builtin_amdgcn_mfma_f32_16x16x32_f16(k1, qfr[qf][1], sa[f][qf], 0, 0, 0);
            }
        }
        // multiplicative diag-zero: only the tile straddling the diagonal
        if (j0 == (wq0 & ~63)) {
            #pragma unroll
            for (int f = 0; f < 4; f++)
                #pragma unroll
                for (int qf = 0; qf < 2; qf++)
                    #pragma unroll
                    for (int r = 0; r < 4; r++) {
                        int q = wq0 + qf * 16 + lr;
                        int kv = j0 + f * 16 + lg * 4 + r;
                        if (q == kv) sa[f][qf][r] = 0.f;
                    }
        }
        // online softmax, per-lane row stats (row = q = lr+16qf)
        #pragma unroll
        for (int qf = 0; qf < 2; qf++) {
            float mx = sa[0][qf][0];
            #pragma unroll
            for (int f = 0; f < 4; f++)
                #pragma unroll
                for (int r = 0; r < 4; r++) mx = fmaxf(mx, sa[f][qf][r]);
            mx = fmaxf(mx, __shfl_xor(mx, 16));
            mx = fmaxf(mx, __shfl_xor(mx, 32));
            float mn = fmaxf(m_[qf], mx);
            float al = __expf(m_[qf] - mn);
            m_[qf] = mn;
            float rs = 0.f;
            #pragma unroll
            for (int f = 0; f < 4; f++) {
                f16x4 pk;
                #pragma unroll
                for (int r = 0; r < 4; r++) {
                    float p = __expf(sa[f][qf][r] - mn);
                    rs += p;
                    pk[r] = (f16)p;
                }
                *(f16x4*)(&Pl[w][qf * 16 + lr][(f * 16 + lg * 4) ^ sw]) = pk;
            }
            rs += __shfl_xor(rs, 16);
            rs += __shfl_xor(rs, 32);
            l_[qf] = l_[qf] * al + rs;
            #pragma unroll
            for (int df = 0; df < 4; df++)
                #pragma unroll
                for (int r = 0; r < 4; r++) po[qf][df][r] *= al;
        }
        asm volatile("s_waitcnt lgkmcnt(0)" ::: "memory");   // wave-local P visibility
        // PV (swapped): ctx^T += V^T x P^T
        f16x8 pf[2][2];
        #pragma unroll
        for (int qf = 0; qf < 2; qf++)
            #pragma unroll
            for (int c = 0; c < 2; c++)
                pf[qf][c] = *(const f16x8*)(&Pl[w][qf * 16 + lr][(c * 32 + lg * 8) ^ sw]);
        #pragma unroll
        for (int df = 0; df < 4; df++) {
            const f16* vr = &Vl[cur][df * 16 + lr][0];
            f16x8 v0 = *(const f16x8*)(vr + ((lg * 8) ^ sw));
            f16x8 v1 = *(const f16x8*)(vr + ((32 + lg * 8) ^ sw));
            #pragma unroll
            for (int qf = 0; qf < 2; qf++) {
                po[qf][df] = __builtin_amdgcn_mfma_f32_16x16x32_f16(v0, pf[qf][0], po[qf][df], 0, 0, 0);
                po[qf][df] = __builtin_amdgcn_mfma_f32_16x16x32_f16(v1, pf[qf][1], po[qf][df], 0, 0, 0);
            }
        }
        __syncthreads();   // tile consumed by all + prefetch drained (vmcnt0 implied)
    }
    // epilogue: lane holds ctx[q=wq0+qf*16+lr][d=df*16+lg*4+r]
    const int b = bh >> 4, h = bh & 15;
    #pragma unroll
    for (int qf = 0; qf < 2; qf++) {
        float inv = 1.f / l_[qf];
        int q = wq0 + qf * 16 + lr;
        f16* cp = ctx + ((size_t)(b * MM + q)) * HD + h * DH;
        #pragma unroll
        for (int df = 0; df < 4; df++) {
            f16x4 o;
            #pragma unroll
            for (int r = 0; r < 4; r++) o[r] = (f16)(po[qf][df][r] * inv);
            *(f16x4*)(cp + df * 16 + lg * 4) = o;
        }
    }
}

// ---------------- output GEMM: out[m,n] = sum_k ctx[m,k] * Wo[n,k] + bo[n] (fp32 out) ----------------
__global__ __launch_bounds__(256) void out_gemm(const f16* __restrict__ A,
                                                const f16* __restrict__ W,
                                                const float* __restrict__ bias,
                                                float* __restrict__ out) {
    __shared__ f16 As[128][40];
    __shared__ f16 Bs[128][40];
    const int bn = blockIdx.x, bm = blockIdx.y;
    const int t = threadIdx.x;
    const int wid = t >> 6, lane = t & 63;
    const int wr = wid >> 1, wc = wid & 1;
    const int lg = lane >> 4, lr = lane & 15;
    f32x4 acc[4][4] = {};

    const int sr = t >> 2;
    const int sc = (t & 3) * 8;
    const f16* Ag = A + (size_t)(bm * 128 + sr) * HD + sc;
    const f16* Wg = W + (size_t)(bn * 128 + sr) * HD + sc;

    for (int k0 = 0; k0 < HD; k0 += 32) {
        f16x8 a0 = *(const f16x8*)(Ag + k0);
        f16x8 a1 = *(const f16x8*)(Ag + (size_t)64 * HD + k0);
        f16x8 b0 = *(const f16x8*)(Wg + k0);
        f16x8 b1 = *(const f16x8*)(Wg + (size_t)64 * HD + k0);
        __syncthreads();
        *(f16x8*)(&As[sr][sc]) = a0;
        *(f16x8*)(&As[sr + 64][sc]) = a1;
        *(f16x8*)(&Bs[sr][sc]) = b0;
        *(f16x8*)(&Bs[sr + 64][sc]) = b1;
        __syncthreads();
        f16x8 af[4], bf[4];
        #pragma unroll
        for (int i = 0; i < 4; i++) af[i] = *(const f16x8*)(&As[wr * 64 + i * 16 + lr][lg * 8]);
        #pragma unroll
        for (int i = 0; i < 4; i++) bf[i] = *(const f16x8*)(&Bs[wc * 64 + i * 16 + lr][lg * 8]);
        #pragma unroll
        for (int i = 0; i < 4; i++)
            #pragma unroll
            for (int j = 0; j < 4; j++)
                acc[i][j] = __builtin_amdgcn_mfma_f32_16x16x32_f16(af[i], bf[j], acc[i][j], 0, 0, 0);
    }

    #pragma unroll
    for (int i = 0; i < 4; i++)
        #pragma unroll
        for (int j = 0; j < 4; j++) {
            int n = bn * 128 + wc * 64 + j * 16 + lr;
            float bv = bias[n];
            #pragma unroll
            for (int r = 0; r < 4; r++) {
                int mg = bm * 128 + wr * 64 + i * 16 + lg * 4 + r;
                out[(size_t)mg * HD + n] = acc[i][j][r] + bv;
            }
        }
}

extern "C" void kernel_launch(void* const* d_in, const int* in_sizes, int n_in,
                              void* d_out, int out_size, void* d_ws, size_t ws_size,
                              hipStream_t stream) {
    const float* x  = (const float*)d_in[0];
    const float* Wq = (const float*)d_in[1];
    const float* bq = (const float*)d_in[2];
    const float* Wk = (const float*)d_in[3];
    const float* bk = (const float*)d_in[4];
    const float* Wv = (const float*)d_in[5];
    const float* bv = (const float*)d_in[6];
    const float* Wo = (const float*)d_in[7];
    const float* bo = (const float*)d_in[8];
    float* out = (float*)d_out;

    f16* xh  = (f16*)d_ws;
    f16* wqh = xh  + (size_t)MT * HD;
    f16* wkh = wqh + (size_t)HD * HD;
    f16* wvh = wkh + (size_t)HD * HD;
    f16* woh = wvh + (size_t)HD * HD;
    f16* Qh  = woh + (size_t)HD * HD;
    f16* Kh  = Qh  + (size_t)BH * MM * DH;
    f16* Vth = Kh  + (size_t)BH * MM * DH;
    f16* ctxh= Vth + (size_t)BH * MM * DH;

    const int xn4 = MT * HD / 4, wn4 = HD * HD / 4;
    cvt_f32_f16<<<(xn4 + 255) / 256, 256, 0, stream>>>(x, xh, xn4);
    cvt_f32_f16<<<(wn4 + 255) / 256, 256, 0, stream>>>(Wq, wqh, wn4);
    cvt_f32_f16<<<(wn4 + 255) / 256, 256, 0, stream>>>(Wk, wkh, wn4);
    cvt_f32_f16<<<(wn4 + 255) / 256, 256, 0, stream>>>(Wv, wvh, wn4);
    cvt_f32_f16<<<(wn4 + 255) / 256, 256, 0, stream>>>(Wo, woh, wn4);

    dim3 gg(HD / 128, MT / 128);   // (8, 32)
    proj_gemm<false, true ><<<gg, 256, 0, stream>>>(xh, wqh, bq, Qh);   // Q pre-scaled by 1/8
    proj_gemm<false, false><<<gg, 256, 0, stream>>>(xh, wkh, bk, Kh);
    proj_gemm<true,  false><<<gg, 256, 0, stream>>>(xh, wvh, bv, Vth);

    attn_kernel<<<dim3(MM / 128, BH), 256, 0, stream>>>(Qh, Kh, Vth, ctxh);

    out_gemm<<<gg, 256, 0, stream>>>(ctxh, woh, bo, out);
}